// Round 2
// baseline (439.550 us; speedup 1.0000x reference)
//
#include <hip/hip_runtime.h>
#include <hip/hip_bf16.h>
#include <math.h>

// LSTM cell fused kernel, MI355X gfx950.
// B=65536, I=128, H=256, O=256, K=I+H=384.
// out = [log_softmax(combined@w_i2o.T+b_i2o) (B*256), new_hidden (B*256)]
//
// v3: TLP fix. v2 showed VALU halved but dur barely moved (206us, Occ 23%,
// MfmaUtil 13%) -> latency-bound with ~1.8 resident blocks/CU.
//  - 512-thread blocks: 8 waves = 2 row-groups x 4 col-groups, per-wave tile 2x4
//    (acc 32 VGPR instead of 64) -> VGPR <=128 (the 16-waves/CU boundary)
//  - __launch_bounds__(512,4) forces the compiler to stay under the cap
//  - 3-slot rotating B prefetch (2 k-steps ahead) + 2-slot A rotation,
//    carried ACROSS phase boundaries (12%3==0, 12%2==0 keeps slots aligned)
//  - phase-0 B primes issued BEFORE LDS staging (hide under stage+barrier)

typedef __attribute__((ext_vector_type(8))) short bf16x8;   // 8 bf16 = 4 VGPRs
typedef __attribute__((ext_vector_type(4))) float f32x4;

#define BM   64     // rows per block
#define LDA  392    // padded LDS row stride in bf16 elems (384+8)
#define NW1  393216 // 1024*384
#define NW2  98304  // 256*384

__device__ __forceinline__ unsigned short f2bf(float f) {
    union { __hip_bfloat16 h; unsigned short u; } cv;
    cv.h = __float2bfloat16(f);
    return cv.u;
}
__device__ __forceinline__ float bf2f(unsigned short u) {
    union { __hip_bfloat16 h; unsigned short u; } cv;
    cv.u = u;
    return __bfloat162float(cv.h);
}
__device__ __forceinline__ float frcp(float x) {            // v_rcp_f32
    return __builtin_amdgcn_rcpf(x);
}
__device__ __forceinline__ float fsigmoid(float x) {
    return frcp(1.0f + __expf(-x));
}
__device__ __forceinline__ float ftanh(float x) {
    // tanh(x) = 1 - 2/(exp(2x)+1); robust at +-inf overflow of __expf
    return 1.0f - 2.0f * frcp(__expf(2.0f * x) + 1.0f);
}

// Convert fp32 weights -> bf16 into workspace. Runs every launch (ws is re-poisoned).
__global__ void conv_w(const float* __restrict__ w1, const float* __restrict__ w2,
                       unsigned short* __restrict__ wb) {
    int idx = blockIdx.x * 256 + threadIdx.x;   // per-float4; total (NW1+NW2)/4 = 122880
    const int n1 = NW1 / 4;
    float4 v;
    if (idx < n1) v = ((const float4*)w1)[idx];
    else          v = ((const float4*)w2)[idx - n1];
    ushort4 u;
    u.x = f2bf(v.x); u.y = f2bf(v.y); u.z = f2bf(v.z); u.w = f2bf(v.w);
    ((ushort4*)wb)[idx] = u;
}

__launch_bounds__(512, 4)
__global__ void lstm_fused(const float* __restrict__ input,    // [B,128]
                           const float* __restrict__ hidden,   // [B,256]
                           const unsigned short* __restrict__ w1b, // bf16 [1024][384]
                           const unsigned short* __restrict__ w2b, // bf16 [256][384]
                           const float* __restrict__ b1,       // [1024]
                           const float* __restrict__ b2,       // [256]
                           float* __restrict__ out_ls,         // [B,256]
                           float* __restrict__ out_nh)         // [B,256]
{
    __shared__ unsigned short A[BM * LDA];      // combined tile, bf16
    __shared__ float red_m[4][BM];
    __shared__ float red_s[4][BM];

    const int tid  = threadIdx.x;
    const int wave = tid >> 6;
    const int lane = tid & 63;
    const int l15  = lane & 15;
    const int quad = lane >> 4;
    const int wg   = wave >> 2;                 // row-group 0..1 (32 rows each)
    const int wc   = wave & 3;                  // col-group 0..3
    const size_t r0 = (size_t)blockIdx.x * BM;

    // ---- phase-0 B pointers + 2 primed k-slices, issued BEFORE staging ----
    const unsigned short* bp[4];
    #pragma unroll
    for (int q = 0; q < 4; ++q)
        bp[q] = w1b + (size_t)(q * 256 + wc * 16 + l15) * 384 + quad * 8;
    bf16x8 bfr[3][4];
    #pragma unroll
    for (int nt = 0; nt < 4; ++nt) bfr[0][nt] = *(const bf16x8*)(bp[nt]);
    #pragma unroll
    for (int nt = 0; nt < 4; ++nt) bfr[1][nt] = *(const bf16x8*)(bp[nt] + 32);

    // ---- stage combined [64 x 384] fp32 -> bf16 LDS ----
    {
        const int row = tid >> 3;            // 0..63 (8 threads per row)
        const int c0  = tid & 7;
        const float4* si = (const float4*)(input  + (r0 + row) * 128);  // 32 float4
        const float4* sh = (const float4*)(hidden + (r0 + row) * 256);  // 64 float4
        ushort4* dst = (ushort4*)&A[row * LDA];
        #pragma unroll
        for (int i = 0; i < 12; ++i) {
            int c4 = c0 + 8 * i;             // 0..95; i<4 -> input cols, else hidden
            float4 v = (i < 4) ? si[c4] : sh[c4 - 32];
            union { __hip_bfloat162 h2; unsigned int u; } p0, p1;
            p0.h2 = __float22bfloat162_rn(make_float2(v.x, v.y));
            p1.h2 = __float22bfloat162_rn(make_float2(v.z, v.w));
            union { ushort4 s4; uint2 u2; } st;
            st.u2 = make_uint2(p0.u, p1.u);
            dst[c4] = st.s4;
        }
    }
    __syncthreads();

    // A-operand per-lane base: A[m = wg*32 + l15][k = quad*8 + j]
    const unsigned short* ap0 = &A[(wg * 32 + l15) * LDA + quad * 8];
    bf16x8 afr[2][2];
    #pragma unroll
    for (int mt = 0; mt < 2; ++mt)
        afr[0][mt] = *(const bf16x8*)(ap0 + mt * 16 * LDA);

    // 5 column phases: 0..3 = gate quadrant-interleaved, 4 = logits.
    #pragma unroll 1
    for (int phase = 0; phase < 5; ++phase) {
        // phase-top scalar/LDS preloads (latency hidden under the 12-step MFMA loop)
        const int j = phase * 64 + wc * 16 + l15;   // gate col (phase<4)
        unsigned short hp[8];
        float bq0, bq1, bq2, bq3;
        float bo[4];
        if (phase < 4) {
            #pragma unroll
            for (int mt = 0; mt < 2; ++mt)
                #pragma unroll
                for (int r = 0; r < 4; ++r)
                    hp[mt * 4 + r] = A[(wg * 32 + mt * 16 + quad * 4 + r) * LDA + 128 + j];
            bq0 = b1[j]; bq1 = b1[256 + j]; bq2 = b1[512 + j]; bq3 = b1[768 + j];
        } else {
            #pragma unroll
            for (int nt = 0; nt < 4; ++nt) bo[nt] = b2[wc * 64 + nt * 16 + l15];
        }

        f32x4 acc[2][4];
        #pragma unroll
        for (int i = 0; i < 2; ++i)
            #pragma unroll
            for (int jj = 0; jj < 4; ++jj)
                acc[i][jj] = (f32x4){0.f, 0.f, 0.f, 0.f};

        #pragma unroll
        for (int kk = 0; kk < 12; ++kk) {
            const int cs  = kk % 3;          // B slot consumed this step
            const int ns  = (kk + 2) % 3;    // B slot filled this step (2 ahead)
            const int as_ = kk & 1;          // A slot consumed
            const int an  = (kk + 1) & 1;    // A slot filled (1 ahead)

            if (kk < 10) {
                #pragma unroll
                for (int nt = 0; nt < 4; ++nt)
                    bfr[ns][nt] = *(const bf16x8*)(bp[nt] + (kk + 2) * 32);
            } else if (kk == 10) {
                // switch pointers and start next phase's k=0 (lands in slot 0: 12%3==0)
                int pn = phase + 1;
                if (pn < 4) {
                    #pragma unroll
                    for (int q = 0; q < 4; ++q)
                        bp[q] = w1b + (size_t)(q * 256 + pn * 64 + wc * 16 + l15) * 384 + quad * 8;
                    #pragma unroll
                    for (int nt = 0; nt < 4; ++nt)
                        bfr[0][nt] = *(const bf16x8*)(bp[nt]);
                } else if (pn == 4) {
                    #pragma unroll
                    for (int nt = 0; nt < 4; ++nt)
                        bp[nt] = w2b + (size_t)(wc * 64 + nt * 16 + l15) * 384 + quad * 8;
                    #pragma unroll
                    for (int nt = 0; nt < 4; ++nt)
                        bfr[0][nt] = *(const bf16x8*)(bp[nt]);
                }
            } else { // kk == 11: next phase's k=1 (slot 1: 13%3==1)
                if (phase < 4) {
                    #pragma unroll
                    for (int nt = 0; nt < 4; ++nt)
                        bfr[1][nt] = *(const bf16x8*)(bp[nt] + 32);
                }
            }
            // A prefetch: 1 ahead; at kk==11 reload k=0 (A is phase-independent)
            if (kk < 11) {
                #pragma unroll
                for (int mt = 0; mt < 2; ++mt)
                    afr[an][mt] = *(const bf16x8*)(ap0 + mt * 16 * LDA + (kk + 1) * 32);
            } else {
                #pragma unroll
                for (int mt = 0; mt < 2; ++mt)
                    afr[0][mt] = *(const bf16x8*)(ap0 + mt * 16 * LDA);
            }

            #pragma unroll
            for (int mt = 0; mt < 2; ++mt)
                #pragma unroll
                for (int nt = 0; nt < 4; ++nt)
                    acc[mt][nt] = __builtin_amdgcn_mfma_f32_16x16x32_bf16(
                        afr[as_][mt], bfr[cs][nt], acc[mt][nt], 0, 0, 0);
        }

        if (phase < 4) {
            // acc[mt][q][r] = gates[row = wg*32 + mt*16 + quad*4 + r][q*256 + j]
            #pragma unroll
            for (int mt = 0; mt < 2; ++mt) {
                #pragma unroll
                for (int r = 0; r < 4; ++r) {
                    int rowl = wg * 32 + mt * 16 + quad * 4 + r;
                    float hprev = bf2f(hp[mt * 4 + r]);
                    float hv  = ftanh(acc[mt][0][r] + bq0);
                    float igv = fsigmoid(acc[mt][1][r] + bq1);
                    float fgv = fsigmoid(acc[mt][2][r] + bq2);
                    float ogv = fsigmoid(acc[mt][3][r] + bq3);
                    out_nh[(r0 + rowl) * 256 + j] = ogv * ftanh(fgv * hprev + igv * hv);
                }
            }
        } else {
            // acc[mt][nt][r] = logits[row][col = wc*64 + nt*16 + l15]
            #pragma unroll
            for (int mt = 0; mt < 2; ++mt)
                #pragma unroll
                for (int nt = 0; nt < 4; ++nt)
                    #pragma unroll
                    for (int r = 0; r < 4; ++r)
                        acc[mt][nt][r] += bo[nt];

            // per-row max: reduce over nt in-lane, then over l15 via xor-butterfly
            float pm[2][4], ps[2][4];
            #pragma unroll
            for (int mt = 0; mt < 2; ++mt)
                #pragma unroll
                for (int r = 0; r < 4; ++r) {
                    float m = acc[mt][0][r];
                    #pragma unroll
                    for (int nt = 1; nt < 4; ++nt) m = fmaxf(m, acc[mt][nt][r]);
                    pm[mt][r] = m;
                }
            #pragma unroll
            for (int mask = 1; mask < 16; mask <<= 1)
                #pragma unroll
                for (int mt = 0; mt < 2; ++mt)
                    #pragma unroll
                    for (int r = 0; r < 4; ++r)
                        pm[mt][r] = fmaxf(pm[mt][r], __shfl_xor(pm[mt][r], mask, 64));
            #pragma unroll
            for (int mt = 0; mt < 2; ++mt)
                #pragma unroll
                for (int r = 0; r < 4; ++r) {
                    float s = 0.f;
                    #pragma unroll
                    for (int nt = 0; nt < 4; ++nt)
                        s += __expf(acc[mt][nt][r] - pm[mt][r]);
                    ps[mt][r] = s;
                }
            #pragma unroll
            for (int mask = 1; mask < 16; mask <<= 1)
                #pragma unroll
                for (int mt = 0; mt < 2; ++mt)
                    #pragma unroll
                    for (int r = 0; r < 4; ++r)
                        ps[mt][r] += __shfl_xor(ps[mt][r], mask, 64);

            if (l15 == 0) {
                #pragma unroll
                for (int mt = 0; mt < 2; ++mt)
                    #pragma unroll
                    for (int r = 0; r < 4; ++r) {
                        int rowl = wg * 32 + mt * 16 + quad * 4 + r;
                        red_m[wc][rowl] = pm[mt][r];
                        red_s[wc][rowl] = ps[mt][r];
                    }
            }
            __syncthreads();
            #pragma unroll
            for (int mt = 0; mt < 2; ++mt)
                #pragma unroll
                for (int r = 0; r < 4; ++r) {
                    int rowl = wg * 32 + mt * 16 + quad * 4 + r;
                    float M = red_m[0][rowl];
                    #pragma unroll
                    for (int w = 1; w < 4; ++w) M = fmaxf(M, red_m[w][rowl]);
                    float S = 0.f;
                    #pragma unroll
                    for (int w = 0; w < 4; ++w)
                        S += red_s[w][rowl] * __expf(red_m[w][rowl] - M);
                    float lz = M + 0.69314718055994531f * __log2f(S);
                    #pragma unroll
                    for (int nt = 0; nt < 4; ++nt)
                        out_ls[(r0 + rowl) * 256 + wc * 64 + nt * 16 + l15] =
                            acc[mt][nt][r] - lz;
                }
        }
    }
}

extern "C" void kernel_launch(void* const* d_in, const int* in_sizes, int n_in,
                              void* d_out, int out_size, void* d_ws, size_t ws_size,
                              hipStream_t stream) {
    const float* input  = (const float*)d_in[0];
    const float* hidden = (const float*)d_in[1];
    const float* w1     = (const float*)d_in[2];
    const float* b1     = (const float*)d_in[3];
    const float* w2     = (const float*)d_in[4];
    const float* b2     = (const float*)d_in[5];
    float* out = (float*)d_out;
    unsigned short* wb = (unsigned short*)d_ws;   // needs 983040 B

    conv_w<<<dim3((NW1 + NW2) / 4 / 256), dim3(256), 0, stream>>>(w1, w2, wb);
    lstm_fused<<<dim3(65536 / BM), dim3(512), 0, stream>>>(
        input, hidden, wb, wb + NW1, b1, b2,
        out, out + (size_t)65536 * 256);
}

// Round 3
// 423.812 us; speedup vs baseline: 1.0371x; 1.0371x over previous
//
#include <hip/hip_runtime.h>
#include <hip/hip_bf16.h>
#include <math.h>

// LSTM cell fused kernel, MI355X gfx950.
// B=65536, I=128, H=256, O=256, K=I+H=384.
// out = [log_softmax(combined@w_i2o.T+b_i2o) (B*256), new_hidden (B*256)]
//
// v4: v3's 8-wave TLP geometry WITHOUT the spills.
//  v3 post-mortem: __launch_bounds__(512,4) behaved as min-BLOCKS-per-CU
//  (CUDA semantics): 4 blk * 8 waves = 32 waves/CU -> VGPR cap 64 -> massive
//  scratch spills (VGPR_Count=64, FETCH +57MB, WRITE +119MB, dur 296us).
//  - __launch_bounds__(512,2): cap 128 under blocks-semantics, 256 under
//    waves/EU-semantics; either way no 64-reg squeeze.
//  - register diet to fit 128: 2-slot B rotation (1-ahead), no A-register
//    rotation (LDS reads scheduled by compiler, hidden by 4-wave/SIMD TLP),
//    next-phase k0 B-prime placed between K-loop and epilogue (hides under
//    the epilogue's ~100+ VALU ops).
//  - LDS 52KB -> 2 blocks/CU resident * 8 waves = 16 waves/CU (50% occ) iff
//    VGPR<=128.

typedef __attribute__((ext_vector_type(8))) short bf16x8;   // 8 bf16 = 4 VGPRs
typedef __attribute__((ext_vector_type(4))) float f32x4;

#define BM   64     // rows per block
#define LDA  392    // padded LDS row stride in bf16 elems (384+8)
#define NW1  393216 // 1024*384
#define NW2  98304  // 256*384

__device__ __forceinline__ unsigned short f2bf(float f) {
    union { __hip_bfloat16 h; unsigned short u; } cv;
    cv.h = __float2bfloat16(f);
    return cv.u;
}
__device__ __forceinline__ float bf2f(unsigned short u) {
    union { __hip_bfloat16 h; unsigned short u; } cv;
    cv.u = u;
    return __bfloat162float(cv.h);
}
__device__ __forceinline__ float frcp(float x) {            // v_rcp_f32
    return __builtin_amdgcn_rcpf(x);
}
__device__ __forceinline__ float fsigmoid(float x) {
    return frcp(1.0f + __expf(-x));
}
__device__ __forceinline__ float ftanh(float x) {
    // tanh(x) = 1 - 2/(exp(2x)+1); robust at +-inf overflow of __expf
    return 1.0f - 2.0f * frcp(__expf(2.0f * x) + 1.0f);
}

// Convert fp32 weights -> bf16 into workspace. Runs every launch (ws is re-poisoned).
__global__ void conv_w(const float* __restrict__ w1, const float* __restrict__ w2,
                       unsigned short* __restrict__ wb) {
    int idx = blockIdx.x * 256 + threadIdx.x;   // per-float4; total (NW1+NW2)/4 = 122880
    const int n1 = NW1 / 4;
    float4 v;
    if (idx < n1) v = ((const float4*)w1)[idx];
    else          v = ((const float4*)w2)[idx - n1];
    ushort4 u;
    u.x = f2bf(v.x); u.y = f2bf(v.y); u.z = f2bf(v.z); u.w = f2bf(v.w);
    ((ushort4*)wb)[idx] = u;
}

__launch_bounds__(512, 2)
__global__ void lstm_fused(const float* __restrict__ input,    // [B,128]
                           const float* __restrict__ hidden,   // [B,256]
                           const unsigned short* __restrict__ w1b, // bf16 [1024][384]
                           const unsigned short* __restrict__ w2b, // bf16 [256][384]
                           const float* __restrict__ b1,       // [1024]
                           const float* __restrict__ b2,       // [256]
                           float* __restrict__ out_ls,         // [B,256]
                           float* __restrict__ out_nh)         // [B,256]
{
    __shared__ unsigned short A[BM * LDA];      // combined tile, bf16
    __shared__ float red_m[4][BM];
    __shared__ float red_s[4][BM];

    const int tid  = threadIdx.x;
    const int wave = tid >> 6;
    const int lane = tid & 63;
    const int l15  = lane & 15;
    const int quad = lane >> 4;
    const int wg   = wave >> 2;                 // row-group 0..1 (32 rows each)
    const int wc   = wave & 3;                  // col-group 0..3
    const size_t r0 = (size_t)blockIdx.x * BM;

    // ---- phase-0 B pointers + k0 prime, issued BEFORE staging ----
    const unsigned short* bp[4];
    #pragma unroll
    for (int q = 0; q < 4; ++q)
        bp[q] = w1b + (size_t)(q * 256 + wc * 16 + l15) * 384 + quad * 8;
    bf16x8 bfr[2][4];
    #pragma unroll
    for (int nt = 0; nt < 4; ++nt) bfr[0][nt] = *(const bf16x8*)(bp[nt]);

    // ---- stage combined [64 x 384] fp32 -> bf16 LDS ----
    {
        const int row = tid >> 3;            // 0..63 (8 threads per row)
        const int c0  = tid & 7;
        const float4* si = (const float4*)(input  + (r0 + row) * 128);  // 32 float4
        const float4* sh = (const float4*)(hidden + (r0 + row) * 256);  // 64 float4
        ushort4* dst = (ushort4*)&A[row * LDA];
        #pragma unroll
        for (int i = 0; i < 12; ++i) {
            int c4 = c0 + 8 * i;             // 0..95; i<4 -> input cols, else hidden
            float4 v = (i < 4) ? si[c4] : sh[c4 - 32];
            union { __hip_bfloat162 h2; unsigned int u; } p0, p1;
            p0.h2 = __float22bfloat162_rn(make_float2(v.x, v.y));
            p1.h2 = __float22bfloat162_rn(make_float2(v.z, v.w));
            union { ushort4 s4; uint2 u2; } st;
            st.u2 = make_uint2(p0.u, p1.u);
            dst[c4] = st.s4;
        }
    }
    __syncthreads();

    // A-operand per-lane base: A[m = wg*32 + l15][k = quad*8 + j]
    const unsigned short* ap0 = &A[(wg * 32 + l15) * LDA + quad * 8];

    // 5 column phases: 0..3 = gate quadrant-interleaved, 4 = logits.
    #pragma unroll 1
    for (int phase = 0; phase < 5; ++phase) {
        // phase-top scalar/LDS preloads (latency hidden under the 12-step MFMA loop)
        const int j = phase * 64 + wc * 16 + l15;   // gate col (phase<4)
        unsigned short hp[8];
        float bq0, bq1, bq2, bq3;
        float bo[4];
        if (phase < 4) {
            #pragma unroll
            for (int mt = 0; mt < 2; ++mt)
                #pragma unroll
                for (int r = 0; r < 4; ++r)
                    hp[mt * 4 + r] = A[(wg * 32 + mt * 16 + quad * 4 + r) * LDA + 128 + j];
            bq0 = b1[j]; bq1 = b1[256 + j]; bq2 = b1[512 + j]; bq3 = b1[768 + j];
        } else {
            #pragma unroll
            for (int nt = 0; nt < 4; ++nt) bo[nt] = b2[wc * 64 + nt * 16 + l15];
        }

        f32x4 acc[2][4];
        #pragma unroll
        for (int i = 0; i < 2; ++i)
            #pragma unroll
            for (int jj = 0; jj < 4; ++jj)
                acc[i][jj] = (f32x4){0.f, 0.f, 0.f, 0.f};

        // K-loop: consume bfr[kk&1], fill bfr[(kk+1)&1] one step ahead.
        #pragma unroll
        for (int kk = 0; kk < 12; ++kk) {
            if (kk < 11) {
                #pragma unroll
                for (int nt = 0; nt < 4; ++nt)
                    bfr[(kk + 1) & 1][nt] = *(const bf16x8*)(bp[nt] + (kk + 1) * 32);
            }
            bf16x8 a0 = *(const bf16x8*)(ap0 + kk * 32);
            bf16x8 a1 = *(const bf16x8*)(ap0 + 16 * LDA + kk * 32);
            #pragma unroll
            for (int nt = 0; nt < 4; ++nt)
                acc[0][nt] = __builtin_amdgcn_mfma_f32_16x16x32_bf16(
                    a0, bfr[kk & 1][nt], acc[0][nt], 0, 0, 0);
            #pragma unroll
            for (int nt = 0; nt < 4; ++nt)
                acc[1][nt] = __builtin_amdgcn_mfma_f32_16x16x32_bf16(
                    a1, bfr[kk & 1][nt], acc[1][nt], 0, 0, 0);
        }

        // Next-phase B pointers + k0 prime into slot 0; latency hides under
        // this phase's epilogue VALU work. (Slot 0 is free: last consume was
        // bfr[1] at kk=11.)
        if (phase < 4) {
            if (phase < 3) {
                int j0 = (phase + 1) * 64 + wc * 16 + l15;
                #pragma unroll
                for (int q = 0; q < 4; ++q)
                    bp[q] = w1b + (size_t)(q * 256 + j0) * 384 + quad * 8;
            } else {
                #pragma unroll
                for (int nt = 0; nt < 4; ++nt)
                    bp[nt] = w2b + (size_t)(wc * 64 + nt * 16 + l15) * 384 + quad * 8;
            }
            #pragma unroll
            for (int nt = 0; nt < 4; ++nt)
                bfr[0][nt] = *(const bf16x8*)(bp[nt]);
        }

        if (phase < 4) {
            // acc[mt][q][r] = gates[row = wg*32 + mt*16 + quad*4 + r][q*256 + j]
            #pragma unroll
            for (int mt = 0; mt < 2; ++mt) {
                #pragma unroll
                for (int r = 0; r < 4; ++r) {
                    int rowl = wg * 32 + mt * 16 + quad * 4 + r;
                    float hprev = bf2f(hp[mt * 4 + r]);
                    float hv  = ftanh(acc[mt][0][r] + bq0);
                    float igv = fsigmoid(acc[mt][1][r] + bq1);
                    float fgv = fsigmoid(acc[mt][2][r] + bq2);
                    float ogv = fsigmoid(acc[mt][3][r] + bq3);
                    out_nh[(r0 + rowl) * 256 + j] = ogv * ftanh(fgv * hprev + igv * hv);
                }
            }
        } else {
            // acc[mt][nt][r] = logits[row][col = wc*64 + nt*16 + l15]
            #pragma unroll
            for (int mt = 0; mt < 2; ++mt)
                #pragma unroll
                for (int nt = 0; nt < 4; ++nt)
                    #pragma unroll
                    for (int r = 0; r < 4; ++r)
                        acc[mt][nt][r] += bo[nt];

            // per-row max: reduce over nt in-lane, then over l15 via xor-butterfly
            float pm[2][4], ps[2][4];
            #pragma unroll
            for (int mt = 0; mt < 2; ++mt)
                #pragma unroll
                for (int r = 0; r < 4; ++r) {
                    float m = acc[mt][0][r];
                    #pragma unroll
                    for (int nt = 1; nt < 4; ++nt) m = fmaxf(m, acc[mt][nt][r]);
                    pm[mt][r] = m;
                }
            #pragma unroll
            for (int mask = 1; mask < 16; mask <<= 1)
                #pragma unroll
                for (int mt = 0; mt < 2; ++mt)
                    #pragma unroll
                    for (int r = 0; r < 4; ++r)
                        pm[mt][r] = fmaxf(pm[mt][r], __shfl_xor(pm[mt][r], mask, 64));
            #pragma unroll
            for (int mt = 0; mt < 2; ++mt)
                #pragma unroll
                for (int r = 0; r < 4; ++r) {
                    float s = 0.f;
                    #pragma unroll
                    for (int nt = 0; nt < 4; ++nt)
                        s += __expf(acc[mt][nt][r] - pm[mt][r]);
                    ps[mt][r] = s;
                }
            #pragma unroll
            for (int mask = 1; mask < 16; mask <<= 1)
                #pragma unroll
                for (int mt = 0; mt < 2; ++mt)
                    #pragma unroll
                    for (int r = 0; r < 4; ++r)
                        ps[mt][r] += __shfl_xor(ps[mt][r], mask, 64);

            if (l15 == 0) {
                #pragma unroll
                for (int mt = 0; mt < 2; ++mt)
                    #pragma unroll
                    for (int r = 0; r < 4; ++r) {
                        int rowl = wg * 32 + mt * 16 + quad * 4 + r;
                        red_m[wc][rowl] = pm[mt][r];
                        red_s[wc][rowl] = ps[mt][r];
                    }
            }
            __syncthreads();
            #pragma unroll
            for (int mt = 0; mt < 2; ++mt)
                #pragma unroll
                for (int r = 0; r < 4; ++r) {
                    int rowl = wg * 32 + mt * 16 + quad * 4 + r;
                    float M = red_m[0][rowl];
                    #pragma unroll
                    for (int w = 1; w < 4; ++w) M = fmaxf(M, red_m[w][rowl]);
                    float S = 0.f;
                    #pragma unroll
                    for (int w = 0; w < 4; ++w)
                        S += red_s[w][rowl] * __expf(red_m[w][rowl] - M);
                    float lz = M + 0.69314718055994531f * __log2f(S);
                    #pragma unroll
                    for (int nt = 0; nt < 4; ++nt)
                        out_ls[(r0 + rowl) * 256 + wc * 64 + nt * 16 + l15] =
                            acc[mt][nt][r] - lz;
                }
        }
    }
}

extern "C" void kernel_launch(void* const* d_in, const int* in_sizes, int n_in,
                              void* d_out, int out_size, void* d_ws, size_t ws_size,
                              hipStream_t stream) {
    const float* input  = (const float*)d_in[0];
    const float* hidden = (const float*)d_in[1];
    const float* w1     = (const float*)d_in[2];
    const float* b1     = (const float*)d_in[3];
    const float* w2     = (const float*)d_in[4];
    const float* b2     = (const float*)d_in[5];
    float* out = (float*)d_out;
    unsigned short* wb = (unsigned short*)d_ws;   // needs 983040 B

    conv_w<<<dim3((NW1 + NW2) / 4 / 256), dim3(256), 0, stream>>>(w1, w2, wb);
    lstm_fused<<<dim3(65536 / BM), dim3(512), 0, stream>>>(
        input, hidden, wb, wb + NW1, b1, b2,
        out, out + (size_t)65536 * 256);
}

// Round 4
// 408.757 us; speedup vs baseline: 1.0753x; 1.0368x over previous
//
#include <hip/hip_runtime.h>
#include <hip/hip_bf16.h>
#include <math.h>

// LSTM cell fused kernel, MI355X gfx950.
// B=65536, I=128, H=256, O=256, K=I+H=384.
// out = [log_softmax(combined@w_i2o.T+b_i2o) (B*256), new_hidden (B*256)]
//
// v5: v2's structure (256t, 64x64 wave tile, 3-slot/2-ahead B rotation)
// WITHOUT the spills and WITH 3 waves/SIMD.
//  Launch-bounds post-mortem across v2/v3/v4: second arg behaves as
//  min-BLOCKS-per-CU: (512,4)->cap 64, (512,2)->cap 128, (256,2)->cap 128ish
//  (v2's 156-reg live set was clamped to 128 -> K-loop scratch spills; its
//  FETCH/WRITE excess vs v0 was spill traffic).
//  - __launch_bounds__(256,3): both plausible semantics give cap ~170 VGPR
//    and a 12 waves/CU target; LDS 52224*3 = 156.7KB fits 3 blocks/CU.
//  - A-register rotation dropped (-32 VGPR): live set ~150-160 fits the cap;
//    A ds_reads are ~120cy, covered by 3-wave/SIMD TLP + compiler lgkmcnt.
//  - B rotation: 3 slots, fill (kk+2)%3 while consuming kk%3; slots carried
//    across phases (12%3==0), next-phase k0/k1 primed at kk=10/11 so their
//    latency hides under this phase's MFMA tail + epilogue VALU.

typedef __attribute__((ext_vector_type(8))) short bf16x8;   // 8 bf16 = 4 VGPRs
typedef __attribute__((ext_vector_type(4))) float f32x4;

#define BM   64     // rows per block
#define LDA  392    // padded LDS row stride in bf16 elems (384+8)
#define NW1  393216 // 1024*384
#define NW2  98304  // 256*384

__device__ __forceinline__ unsigned short f2bf(float f) {
    union { __hip_bfloat16 h; unsigned short u; } cv;
    cv.h = __float2bfloat16(f);
    return cv.u;
}
__device__ __forceinline__ float bf2f(unsigned short u) {
    union { __hip_bfloat16 h; unsigned short u; } cv;
    cv.u = u;
    return __bfloat162float(cv.h);
}
__device__ __forceinline__ float frcp(float x) {            // v_rcp_f32
    return __builtin_amdgcn_rcpf(x);
}
__device__ __forceinline__ float fsigmoid(float x) {
    return frcp(1.0f + __expf(-x));
}
__device__ __forceinline__ float ftanh(float x) {
    // tanh(x) = 1 - 2/(exp(2x)+1); robust at +-inf overflow of __expf
    return 1.0f - 2.0f * frcp(__expf(2.0f * x) + 1.0f);
}

// Convert fp32 weights -> bf16 into workspace. Runs every launch (ws is re-poisoned).
__global__ void conv_w(const float* __restrict__ w1, const float* __restrict__ w2,
                       unsigned short* __restrict__ wb) {
    int idx = blockIdx.x * 256 + threadIdx.x;   // per-float4; total (NW1+NW2)/4 = 122880
    const int n1 = NW1 / 4;
    float4 v;
    if (idx < n1) v = ((const float4*)w1)[idx];
    else          v = ((const float4*)w2)[idx - n1];
    ushort4 u;
    u.x = f2bf(v.x); u.y = f2bf(v.y); u.z = f2bf(v.z); u.w = f2bf(v.w);
    ((ushort4*)wb)[idx] = u;
}

__launch_bounds__(256, 3)
__global__ void lstm_fused(const float* __restrict__ input,    // [B,128]
                           const float* __restrict__ hidden,   // [B,256]
                           const unsigned short* __restrict__ w1b, // bf16 [1024][384]
                           const unsigned short* __restrict__ w2b, // bf16 [256][384]
                           const float* __restrict__ b1,       // [1024]
                           const float* __restrict__ b2,       // [256]
                           float* __restrict__ out_ls,         // [B,256]
                           float* __restrict__ out_nh)         // [B,256]
{
    __shared__ unsigned short A[BM * LDA];      // combined tile, bf16
    __shared__ float red_m[4][BM];
    __shared__ float red_s[4][BM];

    const int tid  = threadIdx.x;
    const int wave = tid >> 6;
    const int lane = tid & 63;
    const int l15  = lane & 15;
    const int quad = lane >> 4;
    const size_t r0 = (size_t)blockIdx.x * BM;

    // ---- phase-0 B pointers + 2 primed k-slices, issued BEFORE staging ----
    const unsigned short* bp[4];
    #pragma unroll
    for (int q = 0; q < 4; ++q)
        bp[q] = w1b + (size_t)(q * 256 + wave * 16 + l15) * 384 + quad * 8;
    bf16x8 bfr[3][4];
    #pragma unroll
    for (int nt = 0; nt < 4; ++nt) bfr[0][nt] = *(const bf16x8*)(bp[nt]);
    #pragma unroll
    for (int nt = 0; nt < 4; ++nt) bfr[1][nt] = *(const bf16x8*)(bp[nt] + 32);

    // ---- stage combined [64 x 384] fp32 -> bf16 LDS ----
    {
        const int row = tid >> 2;            // 0..63 (4 threads per row)
        const int c0  = tid & 3;
        const float4* si = (const float4*)(input  + (r0 + row) * 128);  // 32 float4
        const float4* sh = (const float4*)(hidden + (r0 + row) * 256);  // 64 float4
        ushort4* dst = (ushort4*)&A[row * LDA];
        #pragma unroll
        for (int i = 0; i < 24; ++i) {
            int c4 = c0 + 4 * i;             // 0..95; i<8 -> input cols, else hidden
            float4 v = (i < 8) ? si[c4] : sh[c4 - 32];
            union { __hip_bfloat162 h2; unsigned int u; } p0, p1;
            p0.h2 = __float22bfloat162_rn(make_float2(v.x, v.y));
            p1.h2 = __float22bfloat162_rn(make_float2(v.z, v.w));
            union { ushort4 s4; uint2 u2; } st;
            st.u2 = make_uint2(p0.u, p1.u);
            dst[c4] = st.s4;
        }
    }
    __syncthreads();

    // A-operand per-lane base: A[m = l15][k = quad*8 + j]
    const unsigned short* ap0 = &A[l15 * LDA + quad * 8];

    // 5 column phases: 0..3 = gate quadrant-interleaved, 4 = logits.
    #pragma unroll 1
    for (int phase = 0; phase < 5; ++phase) {
        // phase-top scalar/LDS preloads (latency hidden under the 12-step MFMA loop)
        const int j = phase * 64 + wave * 16 + l15;   // gate col (phase<4)
        unsigned short hp[16];
        float bq0, bq1, bq2, bq3;
        float bo[4];
        if (phase < 4) {
            #pragma unroll
            for (int mt = 0; mt < 4; ++mt)
                #pragma unroll
                for (int r = 0; r < 4; ++r)
                    hp[mt * 4 + r] = A[(mt * 16 + quad * 4 + r) * LDA + 128 + j];
            bq0 = b1[j]; bq1 = b1[256 + j]; bq2 = b1[512 + j]; bq3 = b1[768 + j];
        } else {
            #pragma unroll
            for (int nt = 0; nt < 4; ++nt) bo[nt] = b2[wave * 64 + nt * 16 + l15];
        }

        f32x4 acc[4][4];
        #pragma unroll
        for (int i = 0; i < 4; ++i)
            #pragma unroll
            for (int jj = 0; jj < 4; ++jj)
                acc[i][jj] = (f32x4){0.f, 0.f, 0.f, 0.f};

        // K-loop: consume bfr[kk%3], fill bfr[(kk+2)%3] two steps ahead.
        #pragma unroll
        for (int kk = 0; kk < 12; ++kk) {
            if (kk < 10) {
                #pragma unroll
                for (int nt = 0; nt < 4; ++nt)
                    bfr[(kk + 2) % 3][nt] = *(const bf16x8*)(bp[nt] + (kk + 2) * 32);
            } else if (kk == 10) {
                // switch pointers and prime next phase's k=0 (slot 12%3 == 0)
                int pn = phase + 1;
                if (pn < 4) {
                    #pragma unroll
                    for (int q = 0; q < 4; ++q)
                        bp[q] = w1b + (size_t)(q * 256 + pn * 64 + wave * 16 + l15) * 384 + quad * 8;
                    #pragma unroll
                    for (int nt = 0; nt < 4; ++nt)
                        bfr[0][nt] = *(const bf16x8*)(bp[nt]);
                } else if (pn == 4) {
                    #pragma unroll
                    for (int nt = 0; nt < 4; ++nt)
                        bp[nt] = w2b + (size_t)(wave * 64 + nt * 16 + l15) * 384 + quad * 8;
                    #pragma unroll
                    for (int nt = 0; nt < 4; ++nt)
                        bfr[0][nt] = *(const bf16x8*)(bp[nt]);
                }
            } else { // kk == 11: next phase's k=1 (slot 13%3 == 1)
                if (phase < 4) {
                    #pragma unroll
                    for (int nt = 0; nt < 4; ++nt)
                        bfr[1][nt] = *(const bf16x8*)(bp[nt] + 32);
                }
            }
            bf16x8 a[4];
            #pragma unroll
            for (int mt = 0; mt < 4; ++mt)
                a[mt] = *(const bf16x8*)(ap0 + mt * 16 * LDA + kk * 32);
            #pragma unroll
            for (int mt = 0; mt < 4; ++mt)
                #pragma unroll
                for (int nt = 0; nt < 4; ++nt)
                    acc[mt][nt] = __builtin_amdgcn_mfma_f32_16x16x32_bf16(
                        a[mt], bfr[kk % 3][nt], acc[mt][nt], 0, 0, 0);
        }

        if (phase < 4) {
            // acc[mt][q][r] = gates[row = mt*16+quad*4+r][q*256 + j]
            #pragma unroll
            for (int mt = 0; mt < 4; ++mt) {
                #pragma unroll
                for (int r = 0; r < 4; ++r) {
                    int rowl = mt * 16 + quad * 4 + r;
                    float hprev = bf2f(hp[mt * 4 + r]);
                    float hv  = ftanh(acc[mt][0][r] + bq0);
                    float igv = fsigmoid(acc[mt][1][r] + bq1);
                    float fgv = fsigmoid(acc[mt][2][r] + bq2);
                    float ogv = fsigmoid(acc[mt][3][r] + bq3);
                    out_nh[(r0 + rowl) * 256 + j] = ogv * ftanh(fgv * hprev + igv * hv);
                }
            }
        } else {
            // acc[mt][nt][r] = logits[row][col = wave*64 + nt*16 + l15]
            #pragma unroll
            for (int mt = 0; mt < 4; ++mt)
                #pragma unroll
                for (int nt = 0; nt < 4; ++nt)
                    #pragma unroll
                    for (int r = 0; r < 4; ++r)
                        acc[mt][nt][r] += bo[nt];

            // per-row max: reduce over nt in-lane, then over l15 via xor-butterfly
            float pm[4][4], ps[4][4];
            #pragma unroll
            for (int mt = 0; mt < 4; ++mt)
                #pragma unroll
                for (int r = 0; r < 4; ++r) {
                    float m = acc[mt][0][r];
                    #pragma unroll
                    for (int nt = 1; nt < 4; ++nt) m = fmaxf(m, acc[mt][nt][r]);
                    pm[mt][r] = m;
                }
            #pragma unroll
            for (int mask = 1; mask < 16; mask <<= 1)
                #pragma unroll
                for (int mt = 0; mt < 4; ++mt)
                    #pragma unroll
                    for (int r = 0; r < 4; ++r)
                        pm[mt][r] = fmaxf(pm[mt][r], __shfl_xor(pm[mt][r], mask, 64));
            #pragma unroll
            for (int mt = 0; mt < 4; ++mt)
                #pragma unroll
                for (int r = 0; r < 4; ++r) {
                    float s = 0.f;
                    #pragma unroll
                    for (int nt = 0; nt < 4; ++nt)
                        s += __expf(acc[mt][nt][r] - pm[mt][r]);
                    ps[mt][r] = s;
                }
            #pragma unroll
            for (int mask = 1; mask < 16; mask <<= 1)
                #pragma unroll
                for (int mt = 0; mt < 4; ++mt)
                    #pragma unroll
                    for (int r = 0; r < 4; ++r)
                        ps[mt][r] += __shfl_xor(ps[mt][r], mask, 64);

            if (l15 == 0) {
                #pragma unroll
                for (int mt = 0; mt < 4; ++mt)
                    #pragma unroll
                    for (int r = 0; r < 4; ++r) {
                        int rowl = mt * 16 + quad * 4 + r;
                        red_m[wave][rowl] = pm[mt][r];
                        red_s[wave][rowl] = ps[mt][r];
                    }
            }
            __syncthreads();
            #pragma unroll
            for (int mt = 0; mt < 4; ++mt)
                #pragma unroll
                for (int r = 0; r < 4; ++r) {
                    int rowl = mt * 16 + quad * 4 + r;
                    float M = red_m[0][rowl];
                    #pragma unroll
                    for (int w = 1; w < 4; ++w) M = fmaxf(M, red_m[w][rowl]);
                    float S = 0.f;
                    #pragma unroll
                    for (int w = 0; w < 4; ++w)
                        S += red_s[w][rowl] * __expf(red_m[w][rowl] - M);
                    float lz = M + 0.69314718055994531f * __log2f(S);
                    #pragma unroll
                    for (int nt = 0; nt < 4; ++nt)
                        out_ls[(r0 + rowl) * 256 + wave * 64 + nt * 16 + l15] =
                            acc[mt][nt][r] - lz;
                }
        }
    }
}

extern "C" void kernel_launch(void* const* d_in, const int* in_sizes, int n_in,
                              void* d_out, int out_size, void* d_ws, size_t ws_size,
                              hipStream_t stream) {
    const float* input  = (const float*)d_in[0];
    const float* hidden = (const float*)d_in[1];
    const float* w1     = (const float*)d_in[2];
    const float* b1     = (const float*)d_in[3];
    const float* w2     = (const float*)d_in[4];
    const float* b2     = (const float*)d_in[5];
    float* out = (float*)d_out;
    unsigned short* wb = (unsigned short*)d_ws;   // needs 983040 B

    conv_w<<<dim3((NW1 + NW2) / 4 / 256), dim3(256), 0, stream>>>(w1, w2, wb);
    lstm_fused<<<dim3(65536 / BM), dim3(256), 0, stream>>>(
        input, hidden, wb, wb + NW1, b1, b2,
        out, out + (size_t)65536 * 256);
}

// Round 5
// 316.621 us; speedup vs baseline: 1.3883x; 1.2910x over previous
//
#include <hip/hip_runtime.h>
#include <hip/hip_bf16.h>
#include <math.h>

// LSTM cell fused kernel, MI355X gfx950.
// B=65536, I=128, H=256, O=256, K=I+H=384.
// out = [log_softmax(combined@w_i2o.T+b_i2o) (B*256), new_hidden (B*256)]
//
// v6: 3-blocks/CU via register+LDS diet with a FREE allocator.
//  Cross-round facts: MfmaUtil*dur ~= 26us (MFMA floor) every round; occupancy
//  pinned at ~23% (= 2 blocks of 4 waves). v0/v2 footprint = 116 arch + 64
//  accum = 180/wave -> 12 waves need 2160 > 2048 regs -> 3rd block never fits.
//  Forcing occupancy (v3/v5) makes the compiler split the unified file ~in
//  half and spill (v5: VGPR=84, WRITE 321MB).
//  Fix: get total/wave <= ~165 so 3 blocks fit NATURALLY under (256,2):
//   - 2-slot/1-deep B rotation (32 regs) instead of 3-slot (48)
//   - transient a[4], hp/bias loads moved into epilogues
//   - LDS 52224 -> 50176: softmax red buffers aliased onto the A-tile
//     (A is dead in the phase-4 epilogue; extra __syncthreads guards it)
//  -> 12 waves/CU, 3 waves/SIMD: per-step load latency covered by own
//     1-ahead prefetch (~310cy MFMA issue) + 2 co-waves (~620cy).

typedef __attribute__((ext_vector_type(8))) short bf16x8;   // 8 bf16 = 4 VGPRs
typedef __attribute__((ext_vector_type(4))) float f32x4;

#define BM   64     // rows per block
#define LDA  392    // padded LDS row stride in bf16 elems (384+8)
#define NW1  393216 // 1024*384
#define NW2  98304  // 256*384

__device__ __forceinline__ unsigned short f2bf(float f) {
    union { __hip_bfloat16 h; unsigned short u; } cv;
    cv.h = __float2bfloat16(f);
    return cv.u;
}
__device__ __forceinline__ float bf2f(unsigned short u) {
    union { __hip_bfloat16 h; unsigned short u; } cv;
    cv.u = u;
    return __bfloat162float(cv.h);
}
__device__ __forceinline__ float frcp(float x) {            // v_rcp_f32
    return __builtin_amdgcn_rcpf(x);
}
__device__ __forceinline__ float fsigmoid(float x) {
    return frcp(1.0f + __expf(-x));
}
__device__ __forceinline__ float ftanh(float x) {
    // tanh(x) = 1 - 2/(exp(2x)+1); robust at +-inf overflow of __expf
    return 1.0f - 2.0f * frcp(__expf(2.0f * x) + 1.0f);
}

// Convert fp32 weights -> bf16 into workspace. Runs every launch (ws is re-poisoned).
__global__ void conv_w(const float* __restrict__ w1, const float* __restrict__ w2,
                       unsigned short* __restrict__ wb) {
    int idx = blockIdx.x * 256 + threadIdx.x;   // per-float4; total (NW1+NW2)/4 = 122880
    const int n1 = NW1 / 4;
    float4 v;
    if (idx < n1) v = ((const float4*)w1)[idx];
    else          v = ((const float4*)w2)[idx - n1];
    ushort4 u;
    u.x = f2bf(v.x); u.y = f2bf(v.y); u.z = f2bf(v.z); u.w = f2bf(v.w);
    ((ushort4*)wb)[idx] = u;
}

__launch_bounds__(256, 2)
__global__ void lstm_fused(const float* __restrict__ input,    // [B,128]
                           const float* __restrict__ hidden,   // [B,256]
                           const unsigned short* __restrict__ w1b, // bf16 [1024][384]
                           const unsigned short* __restrict__ w2b, // bf16 [256][384]
                           const float* __restrict__ b1,       // [1024]
                           const float* __restrict__ b2,       // [256]
                           float* __restrict__ out_ls,         // [B,256]
                           float* __restrict__ out_nh)         // [B,256]
{
    // 50176 B. First 2048 B double as red_m/red_s in the phase-4 epilogue
    // (A is dead there; guarded by __syncthreads).
    __shared__ unsigned short A[BM * LDA];

    const int tid  = threadIdx.x;
    const int wave = tid >> 6;
    const int lane = tid & 63;
    const int l15  = lane & 15;
    const int quad = lane >> 4;
    const size_t r0 = (size_t)blockIdx.x * BM;

    // ---- phase-0 B pointers + slot-0 prime, issued BEFORE staging ----
    const unsigned short* bp[4];
    #pragma unroll
    for (int q = 0; q < 4; ++q)
        bp[q] = w1b + (size_t)(q * 256 + wave * 16 + l15) * 384 + quad * 8;
    bf16x8 bfr[2][4];
    #pragma unroll
    for (int nt = 0; nt < 4; ++nt) bfr[0][nt] = *(const bf16x8*)(bp[nt]);

    // ---- stage combined [64 x 384] fp32 -> bf16 LDS ----
    {
        const int row = tid >> 2;            // 0..63 (4 threads per row)
        const int c0  = tid & 3;
        const float4* si = (const float4*)(input  + (r0 + row) * 128);  // 32 float4
        const float4* sh = (const float4*)(hidden + (r0 + row) * 256);  // 64 float4
        ushort4* dst = (ushort4*)&A[row * LDA];
        #pragma unroll
        for (int i = 0; i < 24; ++i) {
            int c4 = c0 + 4 * i;             // 0..95; i<8 -> input cols, else hidden
            float4 v = (i < 8) ? si[c4] : sh[c4 - 32];
            union { __hip_bfloat162 h2; unsigned int u; } p0, p1;
            p0.h2 = __float22bfloat162_rn(make_float2(v.x, v.y));
            p1.h2 = __float22bfloat162_rn(make_float2(v.z, v.w));
            union { ushort4 s4; uint2 u2; } st;
            st.u2 = make_uint2(p0.u, p1.u);
            dst[c4] = st.s4;
        }
    }
    __syncthreads();

    // A-operand per-lane base: A[m = l15][k = quad*8 + j]
    const unsigned short* ap0 = &A[l15 * LDA + quad * 8];

    // 5 column phases: 0..3 = gate quadrant-interleaved, 4 = logits.
    #pragma unroll 1
    for (int phase = 0; phase < 5; ++phase) {
        f32x4 acc[4][4];
        #pragma unroll
        for (int i = 0; i < 4; ++i)
            #pragma unroll
            for (int jj = 0; jj < 4; ++jj)
                acc[i][jj] = (f32x4){0.f, 0.f, 0.f, 0.f};

        // K-loop: consume bfr[kk&1], fill bfr[(kk+1)&1] one step ahead.
        #pragma unroll
        for (int kk = 0; kk < 12; ++kk) {
            if (kk < 11) {
                #pragma unroll
                for (int nt = 0; nt < 4; ++nt)
                    bfr[(kk + 1) & 1][nt] = *(const bf16x8*)(bp[nt] + (kk + 1) * 32);
            }
            bf16x8 a[4];
            #pragma unroll
            for (int mt = 0; mt < 4; ++mt)
                a[mt] = *(const bf16x8*)(ap0 + mt * 16 * LDA + kk * 32);
            #pragma unroll
            for (int mt = 0; mt < 4; ++mt)
                #pragma unroll
                for (int nt = 0; nt < 4; ++nt)
                    acc[mt][nt] = __builtin_amdgcn_mfma_f32_16x16x32_bf16(
                        a[mt], bfr[kk & 1][nt], acc[mt][nt], 0, 0, 0);
        }

        // Next-phase pointers + slot-0 prime (slot 0 free: last consume was
        // bfr[1] at kk=11). Latency hides under this phase's epilogue VALU.
        if (phase < 4) {
            if (phase < 3) {
                int j0 = (phase + 1) * 64 + wave * 16 + l15;
                #pragma unroll
                for (int q = 0; q < 4; ++q)
                    bp[q] = w1b + (size_t)(q * 256 + j0) * 384 + quad * 8;
            } else {
                #pragma unroll
                for (int nt = 0; nt < 4; ++nt)
                    bp[nt] = w2b + (size_t)(wave * 64 + nt * 16 + l15) * 384 + quad * 8;
            }
            #pragma unroll
            for (int nt = 0; nt < 4; ++nt)
                bfr[0][nt] = *(const bf16x8*)(bp[nt]);
        }

        const int j = phase * 64 + wave * 16 + l15;   // output col within group

        if (phase < 4) {
            // acc[mt][q][r] = gates[row = mt*16+quad*4+r][q*256 + j]
            float bq0 = b1[j], bq1 = b1[256 + j], bq2 = b1[512 + j], bq3 = b1[768 + j];
            #pragma unroll
            for (int mt = 0; mt < 4; ++mt) {
                #pragma unroll
                for (int r = 0; r < 4; ++r) {
                    int rowl = mt * 16 + quad * 4 + r;
                    float hprev = bf2f(A[rowl * LDA + 128 + j]);
                    float hv  = ftanh(acc[mt][0][r] + bq0);
                    float igv = fsigmoid(acc[mt][1][r] + bq1);
                    float fgv = fsigmoid(acc[mt][2][r] + bq2);
                    float ogv = fsigmoid(acc[mt][3][r] + bq3);
                    out_nh[(r0 + rowl) * 256 + j] = ogv * ftanh(fgv * hprev + igv * hv);
                }
            }
        } else {
            // acc[mt][nt][r] = logits[row][col = wave*64 + nt*16 + l15]
            float bo[4];
            #pragma unroll
            for (int nt = 0; nt < 4; ++nt) bo[nt] = b2[wave * 64 + nt * 16 + l15];
            #pragma unroll
            for (int mt = 0; mt < 4; ++mt)
                #pragma unroll
                for (int nt = 0; nt < 4; ++nt)
                    #pragma unroll
                    for (int r = 0; r < 4; ++r)
                        acc[mt][nt][r] += bo[nt];

            // per-row max: reduce over nt in-lane, then over l15 via xor-butterfly
            float pm[4][4], ps[4][4];
            #pragma unroll
            for (int mt = 0; mt < 4; ++mt)
                #pragma unroll
                for (int r = 0; r < 4; ++r) {
                    float m = acc[mt][0][r];
                    #pragma unroll
                    for (int nt = 1; nt < 4; ++nt) m = fmaxf(m, acc[mt][nt][r]);
                    pm[mt][r] = m;
                }
            #pragma unroll
            for (int mask = 1; mask < 16; mask <<= 1)
                #pragma unroll
                for (int mt = 0; mt < 4; ++mt)
                    #pragma unroll
                    for (int r = 0; r < 4; ++r)
                        pm[mt][r] = fmaxf(pm[mt][r], __shfl_xor(pm[mt][r], mask, 64));
            #pragma unroll
            for (int mt = 0; mt < 4; ++mt)
                #pragma unroll
                for (int r = 0; r < 4; ++r) {
                    float s = 0.f;
                    #pragma unroll
                    for (int nt = 0; nt < 4; ++nt)
                        s += __expf(acc[mt][nt][r] - pm[mt][r]);
                    ps[mt][r] = s;
                }
            #pragma unroll
            for (int mask = 1; mask < 16; mask <<= 1)
                #pragma unroll
                for (int mt = 0; mt < 4; ++mt)
                    #pragma unroll
                    for (int r = 0; r < 4; ++r)
                        ps[mt][r] += __shfl_xor(ps[mt][r], mask, 64);

            // A is dead from here on; alias its first 2048 B as red buffers.
            __syncthreads();                    // all waves done reading A
            float* red = (float*)A;             // red_m = red[0..255], red_s = red[256..511]
            if (l15 == 0) {
                #pragma unroll
                for (int mt = 0; mt < 4; ++mt)
                    #pragma unroll
                    for (int r = 0; r < 4; ++r) {
                        int rowl = mt * 16 + quad * 4 + r;
                        red[wave * 64 + rowl]       = pm[mt][r];
                        red[256 + wave * 64 + rowl] = ps[mt][r];
                    }
            }
            __syncthreads();
            #pragma unroll
            for (int mt = 0; mt < 4; ++mt)
                #pragma unroll
                for (int r = 0; r < 4; ++r) {
                    int rowl = mt * 16 + quad * 4 + r;
                    float M = red[rowl];
                    #pragma unroll
                    for (int w = 1; w < 4; ++w) M = fmaxf(M, red[w * 64 + rowl]);
                    float S = 0.f;
                    #pragma unroll
                    for (int w = 0; w < 4; ++w)
                        S += red[256 + w * 64 + rowl] * __expf(red[w * 64 + rowl] - M);
                    float lz = M + 0.69314718055994531f * __log2f(S);
                    #pragma unroll
                    for (int nt = 0; nt < 4; ++nt)
                        out_ls[(r0 + rowl) * 256 + wave * 64 + nt * 16 + l15] =
                            acc[mt][nt][r] - lz;
                }
        }
    }
}

extern "C" void kernel_launch(void* const* d_in, const int* in_sizes, int n_in,
                              void* d_out, int out_size, void* d_ws, size_t ws_size,
                              hipStream_t stream) {
    const float* input  = (const float*)d_in[0];
    const float* hidden = (const float*)d_in[1];
    const float* w1     = (const float*)d_in[2];
    const float* b1     = (const float*)d_in[3];
    const float* w2     = (const float*)d_in[4];
    const float* b2     = (const float*)d_in[5];
    float* out = (float*)d_out;
    unsigned short* wb = (unsigned short*)d_ws;   // needs 983040 B

    conv_w<<<dim3((NW1 + NW2) / 4 / 256), dim3(256), 0, stream>>>(w1, w2, wb);
    lstm_fused<<<dim3(65536 / BM), dim3(256), 0, stream>>>(
        input, hidden, wb, wb + NW1, b1, b2,
        out, out + (size_t)65536 * 256);
}